// Round 1
// baseline (419.690 us; speedup 1.0000x reference)
//
#include <hip/hip_runtime.h>
#include <cstdint>
#include <cstddef>

#define DEV __device__ __forceinline__

typedef __attribute__((ext_vector_type(8))) short bf16x8;   // 8 bf16 = 4 VGPRs
typedef __attribute__((ext_vector_type(4))) float f32x4;

static_assert(sizeof(bf16x8) == 16, "frag size");

static constexpr int Bb = 2, Tt = 2048, Dd = 1024, Hh = 16, DHc = 64;
static constexpr int BT = Bb * Tt;  // 4096

DEV unsigned short f2bf(float f) {
  union { float f; unsigned u; } v; v.f = f;
  unsigned r = v.u + 0x7fffu + ((v.u >> 16) & 1u);  // RNE
  return (unsigned short)(r >> 16);
}

DEV void gload16(const unsigned short* g, unsigned short* l) {
  __builtin_amdgcn_global_load_lds((__attribute__((address_space(1))) void*)(g),
                                   (__attribute__((address_space(3))) void*)(l),
                                   16, 0, 0);
}

DEV f32x4 mfma16(bf16x8 a, bf16x8 b, f32x4 c) {
  return __builtin_amdgcn_mfma_f32_16x16x32_bf16(a, b, c, 0, 0, 0);
}

// ---------------------------------------------------------------- conversions
__global__ __launch_bounds__(256) void k_cvt_bf16(const float* __restrict__ in,
                                                  unsigned short* __restrict__ out,
                                                  int n4) {
  int i = blockIdx.x * blockDim.x + threadIdx.x;
  if (i >= n4) return;
  float4 v = reinterpret_cast<const float4*>(in)[i];
  ushort4 o;
  o.x = f2bf(v.x); o.y = f2bf(v.y); o.z = f2bf(v.z); o.w = f2bf(v.w);
  reinterpret_cast<ushort4*>(out)[i] = o;
}

// Wt[n][k] = bf16(W[k][n]);  W is [1024][1024] row-major
__global__ __launch_bounds__(256) void k_transpose_bf16(const float* __restrict__ W,
                                                        unsigned short* __restrict__ Wt) {
  __shared__ float t[32][33];
  const int tx = threadIdx.x, ty = threadIdx.y;  // block (32,8)
  const int n0 = blockIdx.x * 32, k0 = blockIdx.y * 32;
#pragma unroll
  for (int i = 0; i < 4; ++i)
    t[ty + 8 * i][tx] = W[(size_t)(k0 + ty + 8 * i) * Dd + n0 + tx];
  __syncthreads();
#pragma unroll
  for (int i = 0; i < 4; ++i)
    Wt[(size_t)(n0 + ty + 8 * i) * Dd + k0 + tx] = f2bf(t[tx][ty + 8 * i]);
}

// ---------------------------------------------------------------- GEMM
// C[M,N] = A[M,K] @ Bt[N,K]^T + bias;  128x128 tile, BK=32, 4 waves
// MODE 0: out16 at [B,H,T,DH]      (Q,K projections)
// MODE 1: out16 at [B,H,DH,T]      (V projection, pre-transposed for PV)
// MODE 2: v += add32; out32 = v; out16 = bf16(v)   (Wo + x residual)
// MODE 3: v = leaky_relu(v); out16 = bf16(v)       (Wh)
// MODE 4: v += add32; out32 = v                    (Wy + h residual -> d_out)
template <int MODE>
__global__ __launch_bounds__(256, 2) void k_gemm(
    const unsigned short* __restrict__ A, const unsigned short* __restrict__ Bt,
    const float* __restrict__ bias, const float* __restrict__ add32,
    float* __restrict__ out32, unsigned short* __restrict__ out16,
    int M, int N, int K) {
  (void)M;
  __shared__ unsigned short sA[128 * 32];
  __shared__ unsigned short sB[128 * 32];
  const int tid = threadIdx.x;
  const int w = tid >> 6, l = tid & 63;
  const int wr = w >> 1, wc = w & 1;
  const int m0 = blockIdx.y * 128, n0 = blockIdx.x * 128;

  const f32x4 fz = {0.f, 0.f, 0.f, 0.f};
  f32x4 acc[4][4];
#pragma unroll
  for (int m = 0; m < 4; ++m)
#pragma unroll
    for (int n = 0; n < 4; ++n) acc[m][n] = fz;

  const int srow = l >> 2, scol = (l & 3) * 8;
  const unsigned short* pa = A + (size_t)(m0 + w * 32 + srow) * K + scol;
  const unsigned short* pb = Bt + (size_t)(n0 + w * 32 + srow) * K + scol;
  unsigned short* la = &sA[(w * 32) * 32];
  unsigned short* lb = &sB[(w * 32) * 32];
  const int fr = l & 15, fk = (l >> 4) * 8;
  const int ar0 = (wr * 64 + fr) * 32 + fk;
  const int br0 = (wc * 64 + fr) * 32 + fk;

  for (int kt = 0; kt < K; kt += 32) {
    gload16(pa + kt, la);
    gload16(pa + kt + (size_t)16 * K, la + 16 * 32);
    gload16(pb + kt, lb);
    gload16(pb + kt + (size_t)16 * K, lb + 16 * 32);
    __syncthreads();
    bf16x8 af[4], bg[4];
#pragma unroll
    for (int m = 0; m < 4; ++m) af[m] = *(const bf16x8*)&sA[ar0 + m * 16 * 32];
#pragma unroll
    for (int n = 0; n < 4; ++n) bg[n] = *(const bf16x8*)&sB[br0 + n * 16 * 32];
#pragma unroll
    for (int m = 0; m < 4; ++m)
#pragma unroll
      for (int n = 0; n < 4; ++n) acc[m][n] = mfma16(af[m], bg[n], acc[m][n]);
    __syncthreads();
  }

  const int fq4 = (l >> 4) * 4;
#pragma unroll
  for (int n = 0; n < 4; ++n) {
    const int col = n0 + wc * 64 + n * 16 + fr;
    const float bv = bias[col];
#pragma unroll
    for (int m = 0; m < 4; ++m) {
      const int row0 = m0 + wr * 64 + m * 16 + fq4;
#pragma unroll
      for (int j = 0; j < 4; ++j) {
        const int row = row0 + j;
        float v = acc[m][n][j] + bv;
        if constexpr (MODE == 0) {
          const size_t idx =
              (((size_t)(row >> 11) * Hh + (col >> 6)) * Tt + (row & (Tt - 1))) * DHc +
              (col & (DHc - 1));
          out16[idx] = f2bf(v);
        } else if constexpr (MODE == 1) {
          const size_t idx =
              (((size_t)(row >> 11) * Hh + (col >> 6)) * DHc + (col & (DHc - 1))) * Tt +
              (row & (Tt - 1));
          out16[idx] = f2bf(v);
        } else if constexpr (MODE == 2) {
          const size_t idx = (size_t)row * N + col;
          v += add32[idx];
          out32[idx] = v;
          out16[idx] = f2bf(v);
        } else if constexpr (MODE == 3) {
          const size_t idx = (size_t)row * N + col;
          v = v > 0.f ? v : 0.01f * v;
          out16[idx] = f2bf(v);
        } else {
          const size_t idx = (size_t)row * N + col;
          v += add32[idx];
          out32[idx] = v;
        }
      }
    }
  }
}

// ---------------------------------------------------------------- attention
// Q,K: [BH][T][64] bf16; Vt: [BH][64][T] bf16; ctx out: [B][T][D] bf16
// grid (T/64, B*H), 4 waves/block, wave handles 16 q-rows. Flash, KB=64.
__global__ __launch_bounds__(256, 2) void k_attn(const unsigned short* __restrict__ Q,
                                                 const unsigned short* __restrict__ Km,
                                                 const unsigned short* __restrict__ Vt,
                                                 unsigned short* __restrict__ ctx) {
  __shared__ unsigned short P[4][16][72];  // per-wave, padded (144B rows: 16B-aligned)
  const int bh = blockIdx.y;
  const int w = threadIdx.x >> 6, l = threadIdx.x & 63;
  const int q0 = blockIdx.x * 64 + w * 16;
  const int fr = l & 15, fk = (l >> 4) * 8, fq4 = (l >> 4) * 4;

  const unsigned short* Qb = Q + (size_t)bh * Tt * DHc;
  const unsigned short* Kb = Km + (size_t)bh * Tt * DHc;
  const unsigned short* Vb = Vt + (size_t)bh * DHc * Tt;

  const bf16x8 aq0 = *(const bf16x8*)&Qb[(size_t)(q0 + fr) * DHc + fk];
  const bf16x8 aq1 = *(const bf16x8*)&Qb[(size_t)(q0 + fr) * DHc + 32 + fk];

  const f32x4 fz = {0.f, 0.f, 0.f, 0.f};
  f32x4 o[4];
#pragma unroll
  for (int n = 0; n < 4; ++n) o[n] = fz;
  float mr[4], lr[4];
#pragma unroll
  for (int j = 0; j < 4; ++j) { mr[j] = -3e38f; lr[j] = 0.f; }

  for (int kb = 0; kb < Tt; kb += 64) {
    f32x4 s[4];
#pragma unroll
    for (int nf = 0; nf < 4; ++nf) {
      const unsigned short* kp = &Kb[(size_t)(kb + nf * 16 + fr) * DHc + fk];
      s[nf] = mfma16(aq0, *(const bf16x8*)kp, fz);
      s[nf] = mfma16(aq1, *(const bf16x8*)(kp + 32), s[nf]);
    }
    float pmax[4] = {-3e38f, -3e38f, -3e38f, -3e38f};
#pragma unroll
    for (int nf = 0; nf < 4; ++nf)
#pragma unroll
      for (int j = 0; j < 4; ++j) {
        s[nf][j] *= 0.125f;  // 1/sqrt(64)
        pmax[j] = fmaxf(pmax[j], s[nf][j]);
      }
#pragma unroll
    for (int d = 1; d < 16; d <<= 1)
#pragma unroll
      for (int j = 0; j < 4; ++j) pmax[j] = fmaxf(pmax[j], __shfl_xor(pmax[j], d));
    float sc[4], rs[4] = {0.f, 0.f, 0.f, 0.f};
#pragma unroll
    for (int j = 0; j < 4; ++j) {
      const float mn = fmaxf(mr[j], pmax[j]);
      sc[j] = __expf(mr[j] - mn);
      mr[j] = mn;
    }
#pragma unroll
    for (int nf = 0; nf < 4; ++nf)
#pragma unroll
      for (int j = 0; j < 4; ++j) {
        const float p = __expf(s[nf][j] - mr[j]);
        s[nf][j] = p;
        rs[j] += p;
      }
#pragma unroll
    for (int d = 1; d < 16; d <<= 1)
#pragma unroll
      for (int j = 0; j < 4; ++j) rs[j] += __shfl_xor(rs[j], d);
#pragma unroll
    for (int j = 0; j < 4; ++j) lr[j] = lr[j] * sc[j] + rs[j];
#pragma unroll
    for (int n = 0; n < 4; ++n)
#pragma unroll
      for (int j = 0; j < 4; ++j) o[n][j] *= sc[j];
    // P layout swap (score frag layout -> A-frag layout) via per-wave LDS
#pragma unroll
    for (int nf = 0; nf < 4; ++nf)
#pragma unroll
      for (int j = 0; j < 4; ++j) P[w][fq4 + j][nf * 16 + fr] = f2bf(s[nf][j]);
    const bf16x8 pa0 = *(const bf16x8*)&P[w][fr][fk];
    const bf16x8 pa1 = *(const bf16x8*)&P[w][fr][32 + fk];
#pragma unroll
    for (int nf = 0; nf < 4; ++nf) {
      const unsigned short* vp = &Vb[(size_t)(nf * 16 + fr) * Tt + kb + fk];
      o[nf] = mfma16(pa0, *(const bf16x8*)vp, o[nf]);
      o[nf] = mfma16(pa1, *(const bf16x8*)(vp + 32), o[nf]);
    }
  }
  const int b = bh >> 4, h = bh & 15;
#pragma unroll
  for (int nf = 0; nf < 4; ++nf)
#pragma unroll
    for (int j = 0; j < 4; ++j) {
      const float v = o[nf][j] / lr[j];
      ctx[((size_t)(b * Tt + q0 + fq4 + j)) * Dd + h * DHc + nf * 16 + fr] = f2bf(v);
    }
}

// ---------------------------------------------------------------- launch
extern "C" void kernel_launch(void* const* d_in, const int* in_sizes, int n_in,
                              void* d_out, int out_size, void* d_ws, size_t ws_size,
                              hipStream_t stream) {
  (void)in_sizes; (void)n_in; (void)out_size; (void)ws_size;
  const float* x   = (const float*)d_in[0];
  const float* Wq  = (const float*)d_in[1];
  const float* bq  = (const float*)d_in[2];
  const float* Wk  = (const float*)d_in[3];
  const float* bk  = (const float*)d_in[4];
  const float* Wv  = (const float*)d_in[5];
  const float* bv  = (const float*)d_in[6];
  const float* Wo  = (const float*)d_in[7];
  const float* bo  = (const float*)d_in[8];
  const float* Wh  = (const float*)d_in[9];
  const float* bhi = (const float*)d_in[10];
  const float* Wy  = (const float*)d_in[11];
  const float* by  = (const float*)d_in[12];
  float* out = (float*)d_out;

  const size_t EL = (size_t)BT * Dd;  // 4M elements
  unsigned short* slotA = (unsigned short*)d_ws;  // 8MB : x16 -> ctx16 -> act16
  unsigned short* slotB = slotA + EL;             // 8MB : Q16 -> h16
  unsigned short* slotC = slotB + EL;             // 16MB: K16+Vt16 -> h32
  unsigned short* wts   = slotC + 2 * EL;         // 6 x 2MB
  unsigned short* WqT = wts + 0 * (size_t)Dd * Dd;
  unsigned short* WkT = wts + 1 * (size_t)Dd * Dd;
  unsigned short* WvT = wts + 2 * (size_t)Dd * Dd;
  unsigned short* WoT = wts + 3 * (size_t)Dd * Dd;
  unsigned short* WhT = wts + 4 * (size_t)Dd * Dd;
  unsigned short* WyT = wts + 5 * (size_t)Dd * Dd;

  unsigned short* x16   = slotA;
  unsigned short* Q16   = slotB;
  unsigned short* K16   = slotC;
  unsigned short* Vt16  = slotC + EL;
  unsigned short* ctx16 = slotA;            // x16 dead after V projection
  float*          h32   = (float*)slotC;    // K16/Vt16 dead after attention
  unsigned short* h16   = slotB;            // Q16 dead after attention
  unsigned short* act16 = slotA;            // ctx16 dead after Wo GEMM

  k_cvt_bf16<<<dim3((unsigned)(EL / 4 / 256)), 256, 0, stream>>>(x, x16, (int)(EL / 4));
  const dim3 tb(32, 8), tg(32, 32);
  k_transpose_bf16<<<tg, tb, 0, stream>>>(Wq, WqT);
  k_transpose_bf16<<<tg, tb, 0, stream>>>(Wk, WkT);
  k_transpose_bf16<<<tg, tb, 0, stream>>>(Wv, WvT);
  k_transpose_bf16<<<tg, tb, 0, stream>>>(Wo, WoT);
  k_transpose_bf16<<<tg, tb, 0, stream>>>(Wh, WhT);
  k_transpose_bf16<<<tg, tb, 0, stream>>>(Wy, WyT);

  const dim3 gg(Dd / 128, BT / 128);  // (8, 32)
  k_gemm<0><<<gg, 256, 0, stream>>>(x16, WqT, bq, nullptr, nullptr, Q16, BT, Dd, Dd);
  k_gemm<0><<<gg, 256, 0, stream>>>(x16, WkT, bk, nullptr, nullptr, K16, BT, Dd, Dd);
  k_gemm<1><<<gg, 256, 0, stream>>>(x16, WvT, bv, nullptr, nullptr, Vt16, BT, Dd, Dd);

  k_attn<<<dim3(Tt / 64, Bb * Hh), 256, 0, stream>>>(Q16, K16, Vt16, ctx16);

  k_gemm<2><<<gg, 256, 0, stream>>>(ctx16, WoT, bo, x, h32, h16, BT, Dd, Dd);
  k_gemm<3><<<gg, 256, 0, stream>>>(h16, WhT, bhi, nullptr, nullptr, act16, BT, Dd, Dd);
  k_gemm<4><<<gg, 256, 0, stream>>>(act16, WyT, by, h32, out, nullptr, BT, Dd, Dd);
}

// Round 2
// 295.394 us; speedup vs baseline: 1.4208x; 1.4208x over previous
//
#include <hip/hip_runtime.h>
#include <cstdint>
#include <cstddef>

#define DEV __device__ __forceinline__

typedef __attribute__((ext_vector_type(8))) short bf16x8;   // 8 bf16 = 4 VGPRs
typedef __attribute__((ext_vector_type(4))) float f32x4;

static_assert(sizeof(bf16x8) == 16, "frag size");

static constexpr int Bb = 2, Tt = 2048, Dd = 1024, Hh = 16, DHc = 64;
static constexpr int BT = Bb * Tt;  // 4096

DEV unsigned short f2bf(float f) {
  union { float f; unsigned u; } v; v.f = f;
  unsigned r = v.u + 0x7fffu + ((v.u >> 16) & 1u);  // RNE
  return (unsigned short)(r >> 16);
}

DEV void gload16(const void* g, void* l) {
  __builtin_amdgcn_global_load_lds((__attribute__((address_space(1))) void*)(g),
                                   (__attribute__((address_space(3))) void*)(l),
                                   16, 0, 0);
}

DEV f32x4 mfma16(bf16x8 a, bf16x8 b, f32x4 c) {
  return __builtin_amdgcn_mfma_f32_16x16x32_bf16(a, b, c, 0, 0, 0);
}

// ---------------------------------------------------------------- conversions
__global__ __launch_bounds__(256) void k_cvt_bf16(const float* __restrict__ in,
                                                  unsigned short* __restrict__ out,
                                                  int n4) {
  int i = blockIdx.x * blockDim.x + threadIdx.x;
  if (i >= n4) return;
  float4 v = reinterpret_cast<const float4*>(in)[i];
  ushort4 o;
  o.x = f2bf(v.x); o.y = f2bf(v.y); o.z = f2bf(v.z); o.w = f2bf(v.w);
  reinterpret_cast<ushort4*>(out)[i] = o;
}

// Wt[n][k] = bf16(W[k][n]);  W is [1024][1024] row-major
__global__ __launch_bounds__(256) void k_transpose_bf16(const float* __restrict__ W,
                                                        unsigned short* __restrict__ Wt) {
  __shared__ float t[32][33];
  const int tx = threadIdx.x, ty = threadIdx.y;  // block (32,8)
  const int n0 = blockIdx.x * 32, k0 = blockIdx.y * 32;
#pragma unroll
  for (int i = 0; i < 4; ++i)
    t[ty + 8 * i][tx] = W[(size_t)(k0 + ty + 8 * i) * Dd + n0 + tx];
  __syncthreads();
#pragma unroll
  for (int i = 0; i < 4; ++i)
    Wt[(size_t)(n0 + ty + 8 * i) * Dd + k0 + tx] = f2bf(t[tx][ty + 8 * i]);
}

// ---------------------------------------------------------------- GEMM
// C[M,N] = A[M,K] @ Bt[N,K]^T + bias;  128x128 tile, BK=32, 4 waves
// MODE 0: out16 at [B,H,T,DH]      (Q,K projections)
// MODE 1: out16 at [B,H,DH,T]      (V projection, pre-transposed for PV)
// MODE 2: v += add32; out32 = v; out16 = bf16(v)   (Wo + x residual)
// MODE 3: v = leaky_relu(v); out16 = bf16(v)       (Wh)
// MODE 4: v += add32; out32 = v                    (Wy + h residual -> d_out)
template <int MODE>
__global__ __launch_bounds__(256, 2) void k_gemm(
    const unsigned short* __restrict__ A, const unsigned short* __restrict__ Bt,
    const float* __restrict__ bias, const float* __restrict__ add32,
    float* __restrict__ out32, unsigned short* __restrict__ out16,
    int M, int N, int K) {
  (void)M;
  __shared__ unsigned short sA[128 * 32];
  __shared__ unsigned short sB[128 * 32];
  const int tid = threadIdx.x;
  const int w = tid >> 6, l = tid & 63;
  const int wr = w >> 1, wc = w & 1;
  const int m0 = blockIdx.y * 128, n0 = blockIdx.x * 128;

  const f32x4 fz = {0.f, 0.f, 0.f, 0.f};
  f32x4 acc[4][4];
#pragma unroll
  for (int m = 0; m < 4; ++m)
#pragma unroll
    for (int n = 0; n < 4; ++n) acc[m][n] = fz;

  const int srow = l >> 2, scol = (l & 3) * 8;
  const unsigned short* pa = A + (size_t)(m0 + w * 32 + srow) * K + scol;
  const unsigned short* pb = Bt + (size_t)(n0 + w * 32 + srow) * K + scol;
  unsigned short* la = &sA[(w * 32) * 32];
  unsigned short* lb = &sB[(w * 32) * 32];
  const int fr = l & 15, fk = (l >> 4) * 8;
  const int ar0 = (wr * 64 + fr) * 32 + fk;
  const int br0 = (wc * 64 + fr) * 32 + fk;

  for (int kt = 0; kt < K; kt += 32) {
    gload16(pa + kt, la);
    gload16(pa + kt + (size_t)16 * K, la + 16 * 32);
    gload16(pb + kt, lb);
    gload16(pb + kt + (size_t)16 * K, lb + 16 * 32);
    __syncthreads();
    bf16x8 af[4], bg[4];
#pragma unroll
    for (int m = 0; m < 4; ++m) af[m] = *(const bf16x8*)&sA[ar0 + m * 16 * 32];
#pragma unroll
    for (int n = 0; n < 4; ++n) bg[n] = *(const bf16x8*)&sB[br0 + n * 16 * 32];
#pragma unroll
    for (int m = 0; m < 4; ++m)
#pragma unroll
      for (int n = 0; n < 4; ++n) acc[m][n] = mfma16(af[m], bg[n], acc[m][n]);
    __syncthreads();
  }

  const int fq4 = (l >> 4) * 4;
#pragma unroll
  for (int n = 0; n < 4; ++n) {
    const int col = n0 + wc * 64 + n * 16 + fr;
    const float bv = bias[col];
#pragma unroll
    for (int m = 0; m < 4; ++m) {
      const int row0 = m0 + wr * 64 + m * 16 + fq4;
#pragma unroll
      for (int j = 0; j < 4; ++j) {
        const int row = row0 + j;
        float v = acc[m][n][j] + bv;
        if constexpr (MODE == 0) {
          const size_t idx =
              (((size_t)(row >> 11) * Hh + (col >> 6)) * Tt + (row & (Tt - 1))) * DHc +
              (col & (DHc - 1));
          out16[idx] = f2bf(v);
        } else if constexpr (MODE == 1) {
          const size_t idx =
              (((size_t)(row >> 11) * Hh + (col >> 6)) * DHc + (col & (DHc - 1))) * Tt +
              (row & (Tt - 1));
          out16[idx] = f2bf(v);
        } else if constexpr (MODE == 2) {
          const size_t idx = (size_t)row * N + col;
          v += add32[idx];
          out32[idx] = v;
          out16[idx] = f2bf(v);
        } else if constexpr (MODE == 3) {
          const size_t idx = (size_t)row * N + col;
          v = v > 0.f ? v : 0.01f * v;
          out16[idx] = f2bf(v);
        } else {
          const size_t idx = (size_t)row * N + col;
          v += add32[idx];
          out32[idx] = v;
        }
      }
    }
  }
}

// ---------------------------------------------------------------- attention
// Q,K: [BH][T][64] bf16; Vt: [BH][64][T] bf16; ctx out: [B][T][D] bf16
// grid: 512 blocks (16 q-tiles x 32 bh), 4 waves, wave owns 32 q-rows.
// Flash with KB=64, K/V tiles double-buffered in LDS via global_load_lds,
// XOR-swizzled (byte ^= (row&7)<<4) through pre-swizzled global source.
__global__ __launch_bounds__(256, 3) void k_attn(const unsigned short* __restrict__ Q,
                                                 const unsigned short* __restrict__ Km,
                                                 const unsigned short* __restrict__ Vt,
                                                 unsigned short* __restrict__ ctx) {
  __shared__ unsigned short sK[2][64 * 64];
  __shared__ unsigned short sV[2][64 * 64];
  __shared__ unsigned short P[4][32][72];

  // bijective XCD swizzle: 512 blocks, 8 XCDs -> 4 heads' blocks per XCD
  const int pid = blockIdx.x;
  const int logical = (pid & 7) * 64 + (pid >> 3);
  const int bh = logical >> 4;
  const int qt = logical & 15;

  const int w = threadIdx.x >> 6, l = threadIdx.x & 63;
  const int q0 = qt * 128 + w * 32;
  const int fr = l & 15;
  const int fkb = (l >> 4) * 16;      // frag chunk byte offset (0,16,32,48)
  const int fq4 = (l >> 4) * 4;

  const unsigned short* Qb = Q + (size_t)bh * Tt * DHc;
  const char* Kb = (const char*)(Km + (size_t)bh * Tt * DHc);
  const char* Vb = (const char*)(Vt + (size_t)bh * DHc * Tt);

  // Q fragments in registers (read once; L2-resident)
  bf16x8 aq[2][2];
#pragma unroll
  for (int m = 0; m < 2; ++m)
#pragma unroll
    for (int h = 0; h < 2; ++h)
      aq[m][h] = *(const bf16x8*)&Qb[(size_t)(q0 + m * 16 + fr) * DHc + (l >> 4) * 8 + h * 32];

  // per-lane staging source offsets (swizzled): chunk c covers LDS bytes c*16
  const int c0 = w * 128 + l;               // first chunk this lane handles
  const int c1 = c0 + 64;                   // second
  const int r0 = c0 >> 3, r1 = c1 >> 3;     // tile rows
  const int s0 = ((c0 & 7) * 16) ^ ((r0 & 7) << 4);  // swizzled byte-in-row
  const int s1 = ((c1 & 7) * 16) ^ ((r1 & 7) << 4);
  char* dK0 = (char*)sK[0] + (w * 128) * 16;          // wave-uniform LDS bases
  char* dK1 = dK0 + 64 * 16;
  char* dV0 = (char*)sV[0] + (w * 128) * 16;
  char* dV1 = dV0 + 64 * 16;
  const size_t bufStride = (size_t)64 * 64 * 2;       // bytes between buf 0/1

  const f32x4 fz = {0.f, 0.f, 0.f, 0.f};
  f32x4 o[2][4];
#pragma unroll
  for (int m = 0; m < 2; ++m)
#pragma unroll
    for (int n = 0; n < 4; ++n) o[m][n] = fz;
  float mr[2][4], lr[2][4];
#pragma unroll
  for (int m = 0; m < 2; ++m)
#pragma unroll
    for (int j = 0; j < 4; ++j) { mr[m][j] = -3e38f; lr[m][j] = 0.f; }

  constexpr int NT = Tt / 64;  // 32 tiles

  // stage tile 0 into buf 0
  {
    const size_t kbB = 0;
    gload16(Kb + (size_t)r0 * 128 + s0, dK0);
    gload16(Kb + (size_t)r1 * 128 + s1, dK1);
    gload16(Vb + (size_t)r0 * (Tt * 2) + kbB + s0, dV0);
    gload16(Vb + (size_t)r1 * (Tt * 2) + kbB + s1, dV1);
  }
  __syncthreads();

  for (int t = 0; t < NT; ++t) {
    const int buf = t & 1;
    // stage next tile into other buffer (in flight across the compute phase)
    if (t + 1 < NT) {
      const int nb = (t + 1) & 1;
      const size_t kOff = (size_t)(t + 1) * 64 * 128;  // bytes: 64 rows x 128B
      const size_t vOff = (size_t)(t + 1) * 128;       // bytes: 64 cols x 2B
      gload16(Kb + kOff + (size_t)r0 * 128 + s0, dK0 + nb * bufStride);
      gload16(Kb + kOff + (size_t)r1 * 128 + s1, dK1 + nb * bufStride);
      gload16(Vb + (size_t)r0 * (Tt * 2) + vOff + s0, dV0 + nb * bufStride);
      gload16(Vb + (size_t)r1 * (Tt * 2) + vOff + s1, dV1 + nb * bufStride);
    }

    const char* kbuf = (const char*)sK[buf];
    const char* vbuf = (const char*)sV[buf];

    // ---- QK^T
    f32x4 s[2][4];
#pragma unroll
    for (int nf = 0; nf < 4; ++nf) {
      const int row = nf * 16 + fr;
      const int sw = (row & 7) << 4;
      const bf16x8 kf_lo = *(const bf16x8*)(kbuf + row * 128 + (fkb ^ sw));
      const bf16x8 kf_hi = *(const bf16x8*)(kbuf + row * 128 + ((fkb + 64) ^ sw));
#pragma unroll
      for (int m = 0; m < 2; ++m) {
        s[m][nf] = mfma16(aq[m][0], kf_lo, fz);
        s[m][nf] = mfma16(aq[m][1], kf_hi, s[m][nf]);
      }
    }

    // ---- online softmax (per 16-lane row group)
#pragma unroll
    for (int m = 0; m < 2; ++m) {
      float pmax[4] = {-3e38f, -3e38f, -3e38f, -3e38f};
#pragma unroll
      for (int nf = 0; nf < 4; ++nf)
#pragma unroll
        for (int j = 0; j < 4; ++j) {
          s[m][nf][j] *= 0.125f;  // 1/sqrt(64)
          pmax[j] = fmaxf(pmax[j], s[m][nf][j]);
        }
#pragma unroll
      for (int d = 1; d < 16; d <<= 1)
#pragma unroll
        for (int j = 0; j < 4; ++j) pmax[j] = fmaxf(pmax[j], __shfl_xor(pmax[j], d));
      float sc[4], rs[4] = {0.f, 0.f, 0.f, 0.f};
#pragma unroll
      for (int j = 0; j < 4; ++j) {
        const float mn = fmaxf(mr[m][j], pmax[j]);
        sc[j] = __expf(mr[m][j] - mn);
        mr[m][j] = mn;
      }
#pragma unroll
      for (int nf = 0; nf < 4; ++nf)
#pragma unroll
        for (int j = 0; j < 4; ++j) {
          const float p = __expf(s[m][nf][j] - mr[m][j]);
          s[m][nf][j] = p;
          rs[j] += p;
        }
#pragma unroll
      for (int d = 1; d < 16; d <<= 1)
#pragma unroll
        for (int j = 0; j < 4; ++j) rs[j] += __shfl_xor(rs[j], d);
#pragma unroll
      for (int j = 0; j < 4; ++j) lr[m][j] = lr[m][j] * sc[j] + rs[j];
#pragma unroll
      for (int n = 0; n < 4; ++n)
#pragma unroll
        for (int j = 0; j < 4; ++j) o[m][n][j] *= sc[j];
      // P frag-layout swap via per-wave LDS (no block barrier needed)
#pragma unroll
      for (int nf = 0; nf < 4; ++nf)
#pragma unroll
        for (int j = 0; j < 4; ++j)
          P[w][m * 16 + fq4 + j][nf * 16 + fr] = f2bf(s[m][nf][j]);
    }

    bf16x8 pa[2][2];
#pragma unroll
    for (int m = 0; m < 2; ++m)
#pragma unroll
      for (int h = 0; h < 2; ++h)
        pa[m][h] = *(const bf16x8*)&P[w][m * 16 + fr][(l >> 4) * 8 + h * 32];

    // ---- PV
#pragma unroll
    for (int nf = 0; nf < 4; ++nf) {
      const int row = nf * 16 + fr;
      const int sw = (row & 7) << 4;
      const bf16x8 vf_lo = *(const bf16x8*)(vbuf + row * 128 + (fkb ^ sw));
      const bf16x8 vf_hi = *(const bf16x8*)(vbuf + row * 128 + ((fkb + 64) ^ sw));
#pragma unroll
      for (int m = 0; m < 2; ++m) {
        o[m][nf] = mfma16(pa[m][0], vf_lo, o[m][nf]);
        o[m][nf] = mfma16(pa[m][1], vf_hi, o[m][nf]);
      }
    }

    __syncthreads();  // next stage done (vmcnt drain) + all waves past reads
  }

  const int b = bh >> 4, h2 = bh & 15;
#pragma unroll
  for (int m = 0; m < 2; ++m)
#pragma unroll
    for (int nf = 0; nf < 4; ++nf)
#pragma unroll
      for (int j = 0; j < 4; ++j) {
        const float v = o[m][nf][j] / lr[m][j];
        ctx[((size_t)(b * Tt + q0 + m * 16 + fq4 + j)) * Dd + h2 * DHc + nf * 16 + fr] =
            f2bf(v);
      }
}

// ---------------------------------------------------------------- launch
extern "C" void kernel_launch(void* const* d_in, const int* in_sizes, int n_in,
                              void* d_out, int out_size, void* d_ws, size_t ws_size,
                              hipStream_t stream) {
  (void)in_sizes; (void)n_in; (void)out_size; (void)ws_size;
  const float* x   = (const float*)d_in[0];
  const float* Wq  = (const float*)d_in[1];
  const float* bq  = (const float*)d_in[2];
  const float* Wk  = (const float*)d_in[3];
  const float* bk  = (const float*)d_in[4];
  const float* Wv  = (const float*)d_in[5];
  const float* bv  = (const float*)d_in[6];
  const float* Wo  = (const float*)d_in[7];
  const float* bo  = (const float*)d_in[8];
  const float* Wh  = (const float*)d_in[9];
  const float* bhi = (const float*)d_in[10];
  const float* Wy  = (const float*)d_in[11];
  const float* by  = (const float*)d_in[12];
  float* out = (float*)d_out;

  const size_t EL = (size_t)BT * Dd;  // 4M elements
  unsigned short* slotA = (unsigned short*)d_ws;  // 8MB : x16 -> ctx16 -> act16
  unsigned short* slotB = slotA + EL;             // 8MB : Q16 -> h16
  unsigned short* slotC = slotB + EL;             // 16MB: K16+Vt16 -> h32
  unsigned short* wts   = slotC + 2 * EL;         // 6 x 2MB
  unsigned short* WqT = wts + 0 * (size_t)Dd * Dd;
  unsigned short* WkT = wts + 1 * (size_t)Dd * Dd;
  unsigned short* WvT = wts + 2 * (size_t)Dd * Dd;
  unsigned short* WoT = wts + 3 * (size_t)Dd * Dd;
  unsigned short* WhT = wts + 4 * (size_t)Dd * Dd;
  unsigned short* WyT = wts + 5 * (size_t)Dd * Dd;

  unsigned short* x16   = slotA;
  unsigned short* Q16   = slotB;
  unsigned short* K16   = slotC;
  unsigned short* Vt16  = slotC + EL;
  unsigned short* ctx16 = slotA;            // x16 dead after V projection
  float*          h32   = (float*)slotC;    // K16/Vt16 dead after attention
  unsigned short* h16   = slotB;            // Q16 dead after attention
  unsigned short* act16 = slotA;            // ctx16 dead after Wo GEMM

  k_cvt_bf16<<<dim3((unsigned)(EL / 4 / 256)), 256, 0, stream>>>(x, x16, (int)(EL / 4));
  const dim3 tb(32, 8), tg(32, 32);
  k_transpose_bf16<<<tg, tb, 0, stream>>>(Wq, WqT);
  k_transpose_bf16<<<tg, tb, 0, stream>>>(Wk, WkT);
  k_transpose_bf16<<<tg, tb, 0, stream>>>(Wv, WvT);
  k_transpose_bf16<<<tg, tb, 0, stream>>>(Wo, WoT);
  k_transpose_bf16<<<tg, tb, 0, stream>>>(Wh, WhT);
  k_transpose_bf16<<<tg, tb, 0, stream>>>(Wy, WyT);

  const dim3 gg(Dd / 128, BT / 128);  // (8, 32)
  k_gemm<0><<<gg, 256, 0, stream>>>(x16, WqT, bq, nullptr, nullptr, Q16, BT, Dd, Dd);
  k_gemm<0><<<gg, 256, 0, stream>>>(x16, WkT, bk, nullptr, nullptr, K16, BT, Dd, Dd);
  k_gemm<1><<<gg, 256, 0, stream>>>(x16, WvT, bv, nullptr, nullptr, Vt16, BT, Dd, Dd);

  k_attn<<<dim3(512), 256, 0, stream>>>(Q16, K16, Vt16, ctx16);

  k_gemm<2><<<gg, 256, 0, stream>>>(ctx16, WoT, bo, x, h32, h16, BT, Dd, Dd);
  k_gemm<3><<<gg, 256, 0, stream>>>(h16, WhT, bhi, nullptr, nullptr, act16, BT, Dd, Dd);
  k_gemm<4><<<gg, 256, 0, stream>>>(act16, WyT, by, h32, out, nullptr, BT, Dd, Dd);
}

// Round 3
// 182.017 us; speedup vs baseline: 2.3058x; 1.6229x over previous
//
#include <hip/hip_runtime.h>
#include <cstdint>
#include <cstddef>

#define DEV __device__ __forceinline__

typedef __attribute__((ext_vector_type(8))) short bf16x8;    // 8 bf16 = 4 VGPRs
typedef __attribute__((ext_vector_type(4))) float f32x4;
typedef __attribute__((ext_vector_type(16))) float f32x16;

static_assert(sizeof(bf16x8) == 16, "frag size");

static constexpr int Bb = 2, Tt = 2048, Dd = 1024, Hh = 16, DHc = 64;
static constexpr int BT = Bb * Tt;  // 4096

DEV unsigned short f2bf(float f) {
  union { float f; unsigned u; } v; v.f = f;
  unsigned r = v.u + 0x7fffu + ((v.u >> 16) & 1u);  // RNE
  return (unsigned short)(r >> 16);
}

DEV void gload16(const void* g, void* l) {
  __builtin_amdgcn_global_load_lds((__attribute__((address_space(1))) void*)(g),
                                   (__attribute__((address_space(3))) void*)(l),
                                   16, 0, 0);
}

DEV f32x4 mfma16(bf16x8 a, bf16x8 b, f32x4 c) {
  return __builtin_amdgcn_mfma_f32_16x16x32_bf16(a, b, c, 0, 0, 0);
}
DEV f32x16 mfma32(bf16x8 a, bf16x8 b, f32x16 c) {
  return __builtin_amdgcn_mfma_f32_32x32x16_bf16(a, b, c, 0, 0, 0);
}

DEV unsigned cvtpk(float lo, float hi) {
  unsigned r;
  asm("v_cvt_pk_bf16_f32 %0, %1, %2" : "=v"(r) : "v"(lo), "v"(hi));
  return r;
}
DEV void plswap(unsigned& x, unsigned& y) {
  asm volatile("v_permlane32_swap_b32 %0, %1" : "+v"(x), "+v"(y));
}
DEV float exp2g(float x) {
#if __has_builtin(__builtin_amdgcn_exp2f)
  return __builtin_amdgcn_exp2f(x);
#else
  return exp2f(x);
#endif
}

// ---------------------------------------------------------------- conversions
__global__ __launch_bounds__(256) void k_cvt_bf16(const float* __restrict__ in,
                                                  unsigned short* __restrict__ out,
                                                  int n4) {
  int i = blockIdx.x * blockDim.x + threadIdx.x;
  if (i >= n4) return;
  float4 v = reinterpret_cast<const float4*>(in)[i];
  ushort4 o;
  o.x = f2bf(v.x); o.y = f2bf(v.y); o.z = f2bf(v.z); o.w = f2bf(v.w);
  reinterpret_cast<ushort4*>(out)[i] = o;
}

// all 6 weight transposes in one dispatch; dst z-th MB-slab = bf16(W_z^T)
__global__ __launch_bounds__(256) void k_transpose_all(
    const float* __restrict__ W0, const float* __restrict__ W1,
    const float* __restrict__ W2, const float* __restrict__ W3,
    const float* __restrict__ W4, const float* __restrict__ W5,
    unsigned short* __restrict__ dstBase) {
  __shared__ float t[32][33];
  const int z = blockIdx.z;
  const float* W = z == 0 ? W0 : z == 1 ? W1 : z == 2 ? W2 : z == 3 ? W3 : z == 4 ? W4 : W5;
  unsigned short* Wt = dstBase + (size_t)z * Dd * Dd;
  const int tx = threadIdx.x, ty = threadIdx.y;  // block (32,8)
  const int n0 = blockIdx.x * 32, k0 = blockIdx.y * 32;
#pragma unroll
  for (int i = 0; i < 4; ++i)
    t[ty + 8 * i][tx] = W[(size_t)(k0 + ty + 8 * i) * Dd + n0 + tx];
  __syncthreads();
#pragma unroll
  for (int i = 0; i < 4; ++i)
    Wt[(size_t)(n0 + ty + 8 * i) * Dd + k0 + tx] = f2bf(t[tx][ty + 8 * i]);
}

// ---------------------------------------------------------------- fused QKV GEMM
// C[4096,3072] = x16 @ Wqkv^T + bias; 128x128 tile, BK=32, 4 waves, 768 blocks (3/CU)
// cols 0-1023 -> Q[B,H,T,DH]; 1024-2047 -> K[B,H,T,DH]; 2048-3071 -> Vt[B,H,DH,T]
__global__ __launch_bounds__(256, 3) void k_gemm_qkv(
    const unsigned short* __restrict__ A, const unsigned short* __restrict__ Bt,
    const float* __restrict__ bq, const float* __restrict__ bk,
    const float* __restrict__ bv, unsigned short* __restrict__ Qo,
    unsigned short* __restrict__ Ko, unsigned short* __restrict__ Vo) {
  constexpr int K = Dd;
  __shared__ unsigned short sA[128 * 32];
  __shared__ unsigned short sB[128 * 32];
  const int tid = threadIdx.x;
  const int w = tid >> 6, l = tid & 63;
  const int wr = w >> 1, wc = w & 1;
  const int m0 = blockIdx.y * 128, n0 = blockIdx.x * 128;

  const f32x4 fz = {0.f, 0.f, 0.f, 0.f};
  f32x4 acc[4][4];
#pragma unroll
  for (int m = 0; m < 4; ++m)
#pragma unroll
    for (int n = 0; n < 4; ++n) acc[m][n] = fz;

  const int srow = l >> 2, scol = (l & 3) * 8;
  const unsigned short* pa = A + (size_t)(m0 + w * 32 + srow) * K + scol;
  const unsigned short* pb = Bt + (size_t)(n0 + w * 32 + srow) * K + scol;
  unsigned short* la = &sA[(w * 32) * 32];
  unsigned short* lb = &sB[(w * 32) * 32];
  const int fr = l & 15, fk = (l >> 4) * 8;
  const int ar0 = (wr * 64 + fr) * 32 + fk;
  const int br0 = (wc * 64 + fr) * 32 + fk;

  for (int kt = 0; kt < K; kt += 32) {
    gload16(pa + kt, la);
    gload16(pa + kt + (size_t)16 * K, la + 16 * 32);
    gload16(pb + kt, lb);
    gload16(pb + kt + (size_t)16 * K, lb + 16 * 32);
    __syncthreads();
    bf16x8 af[4], bg[4];
#pragma unroll
    for (int m = 0; m < 4; ++m) af[m] = *(const bf16x8*)&sA[ar0 + m * 16 * 32];
#pragma unroll
    for (int n = 0; n < 4; ++n) bg[n] = *(const bf16x8*)&sB[br0 + n * 16 * 32];
#pragma unroll
    for (int m = 0; m < 4; ++m)
#pragma unroll
      for (int n = 0; n < 4; ++n) acc[m][n] = mfma16(af[m], bg[n], acc[m][n]);
    __syncthreads();
  }

  const int fq4 = (l >> 4) * 4;
#pragma unroll
  for (int n = 0; n < 4; ++n) {
    const int col = n0 + wc * 64 + n * 16 + fr;
    const int sect = col >> 10, c = col & 1023;
    const int hh = c >> 6, d = c & 63;
    const float bvl = (sect == 0 ? bq : sect == 1 ? bk : bv)[c];
#pragma unroll
    for (int m = 0; m < 4; ++m) {
      const int row0 = m0 + wr * 64 + m * 16 + fq4;
#pragma unroll
      for (int j = 0; j < 4; ++j) {
        const int row = row0 + j;
        const int b = row >> 11, t = row & (Tt - 1);
        const float v = acc[m][n][j] + bvl;
        if (sect < 2) {
          unsigned short* dst = sect ? Ko : Qo;
          dst[((size_t)(b * Hh + hh) * Tt + t) * DHc + d] = f2bf(v);
        } else {
          Vo[((size_t)(b * Hh + hh) * DHc + d) * Tt + t] = f2bf(v);
        }
      }
    }
  }
}

// ---------------------------------------------------------------- small GEMM (BN=64)
// C[4096,1024] = A @ Bt^T + bias; 128x64 tile, BK=32, 4 waves (2x2), 512 blocks (2/CU)
// MODE 2: v += add32; out32 = v; out16 = bf16(v)   (Wo + x residual)
// MODE 3: v = leaky_relu(v); out16 = bf16(v)       (Wh)
// MODE 4: v += add32; out32 = v                    (Wy + h residual -> d_out)
template <int MODE>
__global__ __launch_bounds__(256, 2) void k_gemm2(
    const unsigned short* __restrict__ A, const unsigned short* __restrict__ Bt,
    const float* __restrict__ bias, const float* __restrict__ add32,
    float* __restrict__ out32, unsigned short* __restrict__ out16) {
  constexpr int K = Dd, N = Dd;
  __shared__ unsigned short sA[128 * 32];
  __shared__ unsigned short sB[64 * 32];
  const int tid = threadIdx.x;
  const int w = tid >> 6, l = tid & 63;
  const int wr = w >> 1, wc = w & 1;
  const int m0 = blockIdx.y * 128, n0 = blockIdx.x * 64;

  const f32x4 fz = {0.f, 0.f, 0.f, 0.f};
  f32x4 acc[4][2];
#pragma unroll
  for (int m = 0; m < 4; ++m)
#pragma unroll
    for (int n = 0; n < 2; ++n) acc[m][n] = fz;

  const unsigned short* pa = A + (size_t)(m0 + w * 32 + (l >> 2)) * K + (l & 3) * 8;
  const unsigned short* pb = Bt + (size_t)(n0 + w * 16 + (l >> 2)) * K + (l & 3) * 8;
  unsigned short* la = &sA[(w * 32) * 32];
  unsigned short* lb = &sB[(w * 16) * 32];
  const int fr = l & 15, fk = (l >> 4) * 8;
  const int ar0 = (wr * 64 + fr) * 32 + fk;
  const int br0 = (wc * 32 + fr) * 32 + fk;

  for (int kt = 0; kt < K; kt += 32) {
    gload16(pa + kt, la);
    gload16(pa + kt + (size_t)16 * K, la + 16 * 32);
    gload16(pb + kt, lb);
    __syncthreads();
    bf16x8 af[4], bg[2];
#pragma unroll
    for (int m = 0; m < 4; ++m) af[m] = *(const bf16x8*)&sA[ar0 + m * 16 * 32];
#pragma unroll
    for (int n = 0; n < 2; ++n) bg[n] = *(const bf16x8*)&sB[br0 + n * 16 * 32];
#pragma unroll
    for (int m = 0; m < 4; ++m)
#pragma unroll
      for (int n = 0; n < 2; ++n) acc[m][n] = mfma16(af[m], bg[n], acc[m][n]);
    __syncthreads();
  }

  const int fq4 = (l >> 4) * 4;
#pragma unroll
  for (int n = 0; n < 2; ++n) {
    const int col = n0 + wc * 32 + n * 16 + fr;
    const float bvl = bias[col];
#pragma unroll
    for (int m = 0; m < 4; ++m) {
      const int row0 = m0 + wr * 64 + m * 16 + fq4;
#pragma unroll
      for (int j = 0; j < 4; ++j) {
        const int row = row0 + j;
        const size_t idx = (size_t)row * N + col;
        float v = acc[m][n][j] + bvl;
        if constexpr (MODE == 2) {
          v += add32[idx];
          out32[idx] = v;
          out16[idx] = f2bf(v);
        } else if constexpr (MODE == 3) {
          v = v > 0.f ? v : 0.01f * v;
          out16[idx] = f2bf(v);
        } else {
          v += add32[idx];
          out32[idx] = v;
        }
      }
    }
  }
}

// ---------------------------------------------------------------- attention
// Q,K: [BH][T][64] bf16; Vt: [BH][64][T] bf16; ctx out: [B][T][D] bf16
// 512 blocks (16 q-tiles x 32 bh), 4 waves, wave owns 32 q-rows.
// Swapped-operand 32x32x16 MFMA: S^T = K.Q^T (lane q = l&31), in-register
// softmax, P->bf16 via cvt_pk + permlane32_swap, O^T = V.P^T (lane q local).
__global__ __launch_bounds__(256, 2) void k_attn(const unsigned short* __restrict__ Q,
                                                 const unsigned short* __restrict__ Km,
                                                 const unsigned short* __restrict__ Vt,
                                                 unsigned short* __restrict__ ctx) {
  __shared__ unsigned short sK[2][64 * 64];
  __shared__ unsigned short sV[2][64 * 64];

  // bijective XCD swizzle: 512 blocks, 8 XCDs
  const int pid = blockIdx.x;
  const int logical = (pid & 7) * 64 + (pid >> 3);
  const int bh = logical >> 4;
  const int qt = logical & 15;

  const int w = threadIdx.x >> 6, l = threadIdx.x & 63;
  const int h = l >> 5, lq = l & 31;
  const int q0w = qt * 128 + w * 32;

  const unsigned short* Qb = Q + (size_t)bh * Tt * DHc;
  const char* Kb = (const char*)(Km + (size_t)bh * Tt * DHc);
  const char* Vb = (const char*)(Vt + (size_t)bh * DHc * Tt);

  // Q^T B-frags: lane needs Q[q0w+lq][cs*16 + h*8 + e]
  bf16x8 qf[4];
  {
    const unsigned short* Qrow = Qb + (size_t)(q0w + lq) * DHc;
#pragma unroll
    for (int cs = 0; cs < 4; ++cs) qf[cs] = *(const bf16x8*)&Qrow[cs * 16 + h * 8];
  }

  // staging offsets (swizzled source, linear LDS dest)
  const int c0 = w * 128 + l;
  const int c1 = c0 + 64;
  const int r0 = c0 >> 3, r1 = c1 >> 3;
  const int s0o = ((c0 & 7) * 16) ^ ((r0 & 7) << 4);
  const int s1o = ((c1 & 7) * 16) ^ ((r1 & 7) << 4);
  char* dK0 = (char*)sK[0] + (w * 128) * 16;
  char* dK1 = dK0 + 64 * 16;
  char* dV0 = (char*)sV[0] + (w * 128) * 16;
  char* dV1 = dV0 + 64 * 16;
  const size_t bufStride = (size_t)64 * 64 * 2;

  f32x16 o0 = {}, o1 = {};
  float mr = -3e38f, lr = 0.f;
  constexpr float C2 = 0.18033688011112042f;  // 0.125 * log2(e)

  constexpr int NT = Tt / 64;

  gload16(Kb + (size_t)r0 * 128 + s0o, dK0);
  gload16(Kb + (size_t)r1 * 128 + s1o, dK1);
  gload16(Vb + (size_t)r0 * (Tt * 2) + s0o, dV0);
  gload16(Vb + (size_t)r1 * (Tt * 2) + s1o, dV1);
  __syncthreads();

  const int swl = (lq & 7) << 4;  // read swizzle: rows lq and lq+32 share (row&7)

  for (int t = 0; t < NT; ++t) {
    const int buf = t & 1;
    if (t + 1 < NT) {
      const int nb = (t + 1) & 1;
      const size_t kOff = (size_t)(t + 1) * 64 * 128;
      const size_t vOff = (size_t)(t + 1) * 128;
      gload16(Kb + kOff + (size_t)r0 * 128 + s0o, dK0 + nb * bufStride);
      gload16(Kb + kOff + (size_t)r1 * 128 + s1o, dK1 + nb * bufStride);
      gload16(Vb + (size_t)r0 * (Tt * 2) + vOff + s0o, dV0 + nb * bufStride);
      gload16(Vb + (size_t)r1 * (Tt * 2) + vOff + s1o, dV1 + nb * bufStride);
    }

    const char* kbuf = (const char*)sK[buf];
    const char* vbuf = (const char*)sV[buf];

    // ---- S^T = K . Q^T  (lane: q = lq; k-rows in regs, split across lane halves)
    f32x16 s0v = {}, s1v = {};
    const char* krow0 = kbuf + lq * 128;
    const char* krow1 = kbuf + (32 + lq) * 128;
#pragma unroll
    for (int cs = 0; cs < 4; ++cs) {
      const int cb = (cs * 32 + h * 16) ^ swl;
      s0v = mfma32(*(const bf16x8*)(krow0 + cb), qf[cs], s0v);
      s1v = mfma32(*(const bf16x8*)(krow1 + cb), qf[cs], s1v);
    }

    // ---- in-register online softmax (q lane-local)
    float smax = -3e38f;
#pragma unroll
    for (int r = 0; r < 16; ++r) smax = fmaxf(smax, fmaxf(s0v[r], s1v[r]));
    smax = fmaxf(smax, __shfl_xor(smax, 32));
    const float mn = fmaxf(mr, smax);
    const float sc = exp2g((mr - mn) * C2);
    mr = mn;
    float rs = 0.f;
#pragma unroll
    for (int r = 0; r < 16; ++r) {
      const float p0 = exp2g((s0v[r] - mn) * C2);
      const float p1 = exp2g((s1v[r] - mn) * C2);
      s0v[r] = p0; s1v[r] = p1;
      rs += p0 + p1;
    }
    rs += __shfl_xor(rs, 32);
    lr = lr * sc + rs;
#pragma unroll
    for (int r = 0; r < 16; ++r) { o0[r] *= sc; o1[r] *= sc; }

    // ---- pack P^T to bf16 B-frags (cvt_pk + permlane32_swap)
    union Uv { unsigned u[4]; bf16x8 v; } uu;
    bf16x8 pb00, pb01, pb10, pb11;
    {
      unsigned a = cvtpk(s0v[0], s0v[1]), b2 = cvtpk(s0v[2], s0v[3]);
      unsigned c = cvtpk(s0v[4], s0v[5]), d2 = cvtpk(s0v[6], s0v[7]);
      plswap(c, a); plswap(d2, b2);
      uu.u[0] = a; uu.u[1] = b2; uu.u[2] = c; uu.u[3] = d2; pb00 = uu.v;
      unsigned e = cvtpk(s0v[8], s0v[9]), f = cvtpk(s0v[10], s0v[11]);
      unsigned g = cvtpk(s0v[12], s0v[13]), h2 = cvtpk(s0v[14], s0v[15]);
      plswap(g, e); plswap(h2, f);
      uu.u[0] = e; uu.u[1] = f; uu.u[2] = g; uu.u[3] = h2; pb01 = uu.v;
    }
    {
      unsigned a = cvtpk(s1v[0], s1v[1]), b2 = cvtpk(s1v[2], s1v[3]);
      unsigned c = cvtpk(s1v[4], s1v[5]), d2 = cvtpk(s1v[6], s1v[7]);
      plswap(c, a); plswap(d2, b2);
      uu.u[0] = a; uu.u[1] = b2; uu.u[2] = c; uu.u[3] = d2; pb10 = uu.v;
      unsigned e = cvtpk(s1v[8], s1v[9]), f = cvtpk(s1v[10], s1v[11]);
      unsigned g = cvtpk(s1v[12], s1v[13]), h2 = cvtpk(s1v[14], s1v[15]);
      plswap(g, e); plswap(h2, f);
      uu.u[0] = e; uu.u[1] = f; uu.u[2] = g; uu.u[3] = h2; pb11 = uu.v;
    }

    // ---- O^T += V . P^T   (lane: q = lq; d-rows in regs)
    const char* vrow0 = vbuf + lq * 128;
    const char* vrow1 = vbuf + (32 + lq) * 128;
    o0 = mfma32(*(const bf16x8*)(vrow0 + ((0 + h * 16) ^ swl)), pb00, o0);
    o0 = mfma32(*(const bf16x8*)(vrow0 + ((32 + h * 16) ^ swl)), pb01, o0);
    o0 = mfma32(*(const bf16x8*)(vrow0 + ((64 + h * 16) ^ swl)), pb10, o0);
    o0 = mfma32(*(const bf16x8*)(vrow0 + ((96 + h * 16) ^ swl)), pb11, o0);
    o1 = mfma32(*(const bf16x8*)(vrow1 + ((0 + h * 16) ^ swl)), pb00, o1);
    o1 = mfma32(*(const bf16x8*)(vrow1 + ((32 + h * 16) ^ swl)), pb01, o1);
    o1 = mfma32(*(const bf16x8*)(vrow1 + ((64 + h * 16) ^ swl)), pb10, o1);
    o1 = mfma32(*(const bf16x8*)(vrow1 + ((96 + h * 16) ^ swl)), pb11, o1);

    __syncthreads();
  }

  // ---- epilogue: O^T[d][q]/lr -> ctx[b, q, h*64+d]  (q = lq lane-local)
  const int b = bh >> 4, hh = bh & 15;
  unsigned short* crow = ctx + ((size_t)(b * Tt + q0w + lq)) * Dd + hh * DHc;
  const float inv = 1.f / lr;
#pragma unroll
  for (int r = 0; r < 16; r += 2) {
    const int d = (r & 3) + 8 * (r >> 2) + 4 * h;
    const unsigned u0 = cvtpk(o0[r] * inv, o0[r + 1] * inv);
    const unsigned u1 = cvtpk(o1[r] * inv, o1[r + 1] * inv);
    *(unsigned*)(crow + d) = u0;
    *(unsigned*)(crow + 32 + d) = u1;
  }
}

// ---------------------------------------------------------------- launch
extern "C" void kernel_launch(void* const* d_in, const int* in_sizes, int n_in,
                              void* d_out, int out_size, void* d_ws, size_t ws_size,
                              hipStream_t stream) {
  (void)in_sizes; (void)n_in; (void)out_size; (void)ws_size;
  const float* x   = (const float*)d_in[0];
  const float* Wq  = (const float*)d_in[1];
  const float* bq  = (const float*)d_in[2];
  const float* Wk  = (const float*)d_in[3];
  const float* bk  = (const float*)d_in[4];
  const float* Wv  = (const float*)d_in[5];
  const float* bv  = (const float*)d_in[6];
  const float* Wo  = (const float*)d_in[7];
  const float* bo  = (const float*)d_in[8];
  const float* Wh  = (const float*)d_in[9];
  const float* bhi = (const float*)d_in[10];
  const float* Wy  = (const float*)d_in[11];
  const float* by  = (const float*)d_in[12];
  float* out = (float*)d_out;

  const size_t EL = (size_t)BT * Dd;  // 4M elements
  const size_t M1 = (size_t)Dd * Dd;  // 1M elements
  unsigned short* slotA = (unsigned short*)d_ws;  // 8MB : x16 -> ctx16 -> act16
  unsigned short* slotB = slotA + EL;             // 8MB : Q16 -> h16
  unsigned short* slotC = slotB + EL;             // 16MB: K16+Vt16 -> h32
  unsigned short* wts   = slotC + 2 * EL;         // 12MB: [Wqkv^T 3M][Wo^T][Wh^T][Wy^T]
  unsigned short* WqkvT = wts;
  unsigned short* WoT   = wts + 3 * M1;
  unsigned short* WhT   = wts + 4 * M1;
  unsigned short* WyT   = wts + 5 * M1;

  unsigned short* x16   = slotA;
  unsigned short* Q16   = slotB;
  unsigned short* K16   = slotC;
  unsigned short* Vt16  = slotC + EL;
  unsigned short* ctx16 = slotA;            // x16 dead after QKV GEMM
  float*          h32   = (float*)slotC;    // K16/Vt16 dead after attention
  unsigned short* h16   = slotB;            // Q16 dead after attention
  unsigned short* act16 = slotA;            // ctx16 dead after Wo GEMM

  k_cvt_bf16<<<dim3((unsigned)(EL / 4 / 256)), 256, 0, stream>>>(x, x16, (int)(EL / 4));
  k_transpose_all<<<dim3(32, 32, 6), dim3(32, 8), 0, stream>>>(Wq, Wk, Wv, Wo, Wh, Wy, wts);

  k_gemm_qkv<<<dim3(24, 32), 256, 0, stream>>>(x16, WqkvT, bq, bk, bv, Q16, K16, Vt16);

  k_attn<<<dim3(512), 256, 0, stream>>>(Q16, K16, Vt16, ctx16);

  const dim3 g2(16, 32);
  k_gemm2<2><<<g2, 256, 0, stream>>>(ctx16, WoT, bo, x, h32, h16);
  k_gemm2<3><<<g2, 256, 0, stream>>>(h16, WhT, bhi, nullptr, nullptr, act16);
  k_gemm2<4><<<g2, 256, 0, stream>>>(act16, WyT, by, h32, out, nullptr);
}